// Round 4
// baseline (1138.916 us; speedup 1.0000x reference)
//
#include <hip/hip_runtime.h>

// Problem constants
#define TT 2000
#define NN 64
#define CC 512
#define SS 200
#define LL 401          // 2*S+1 extended states
#define PF 8            // global prefetch depth (rows)
#define LN2 0.69314718055994530942f

// One wave (64 lanes) per batch element. Lane l owns states 8l..8l+7.
// Linear-domain alpha with PER-LANE exact power-of-2 scaling (block floating
// point): true_alpha = stored * 2^logM[lane]. A wave-global scale cannot work:
// the alpha profile across states spans ~1400 bits while fp32 holds ~126, and
// the final-readout-dominant corridor (s~0.2t) sits far below the running max
// corridor (s~min(2tl,t/2)) -> it flushed to 0 and inflated the loss by
// ~450 nats (the round-3 error of 3.0). Per-lane windows span <90 bits. The
// single cross-lane transfer per step is frame-converted via 2^(dLogM).
__global__ __launch_bounds__(64, 1)
void ctc_alpha(const float* __restrict__ lp,        // (T,N,C)
               const int*  __restrict__ targets,    // (N,S)
               const int*  __restrict__ in_len,     // (N)
               const int*  __restrict__ tgt_len,    // (N)
               float*      __restrict__ loss_ws)    // (N)
{
    const int n = blockIdx.x;
    const int l = threadIdx.x;          // lane 0..63

    __shared__ float rowbuf[2][CC];     // double-buffered log-prob row
    __shared__ float lmArr[64];         // per-lane logM for the epilogue

    const int tl   = tgt_len[n];
    const int smax = 2 * tl;            // highest state we ever need

    // ---- static lattice info: odd states j=1,3,5,7 -> labels ----
    int   cls[4];
    float allowm[4];
    #pragma unroll
    for (int q = 0; q < 4; ++q) {
        int s   = 8 * l + 2 * q + 1;
        int pos = (s - 1) >> 1;
        int posc = pos < SS ? pos : SS - 1;          // clamp (lanes past L=401)
        int c    = targets[n * SS + posc];
        int pm   = pos - 1 < 0 ? 0 : (pos - 1 < SS ? pos - 1 : SS - 1);
        int cp   = targets[n * SS + pm];
        cls[q]    = c;
        allowm[q] = (pos >= 1 && c != cp) ? 1.0f : 0.0f;   // skip s-2 -> s
    }
    // per-state validity mask (state 8l+j alive iff <= smax)
    float m0 = (8*l+0 <= smax) ? 1.f : 0.f;
    float m1 = (8*l+1 <= smax) ? 1.f : 0.f;
    float m2 = (8*l+2 <= smax) ? 1.f : 0.f;
    float m3 = (8*l+3 <= smax) ? 1.f : 0.f;
    float m4 = (8*l+4 <= smax) ? 1.f : 0.f;
    float m5 = (8*l+5 <= smax) ? 1.f : 0.f;
    float m6 = (8*l+6 <= smax) ? 1.f : 0.f;
    float m7 = (8*l+7 <= smax) ? 1.f : 0.f;

    const int inlen = in_len[n];
    const int tEnd  = inlen < TT ? inlen : TT;       // alpha frozen past inlen

    const size_t rowstride = (size_t)NN * CC;
    const float* lpn = lp + (size_t)n * CC + 8 * l;  // lane base: col 8l of row 0

    // ---- stage row 0, init alpha_0 ----
    {
        float4 a = *(const float4*)(lpn);
        float4 b = *(const float4*)(lpn + 4);
        *(float4*)&rowbuf[0][8 * l]     = a;
        *(float4*)&rowbuf[0][8 * l + 4] = b;
    }
    __syncthreads();
    float i_blank = rowbuf[0][0];
    float i_lab0  = rowbuf[0][cls[0]];

    float S0=0.f,S1=0.f,S2=0.f,S3=0.f,S4=0.f,S5=0.f,S6=0.f,S7=0.f;
    bool active = (l == 0);
    if (l == 0) {
        S0 = __expf(i_blank);   // state 0 (blank)
        S1 = __expf(i_lab0);    // state 1 (first label)
    }
    float logM = 0.0f;          // per-lane accumulated log2 scale

    // ---- stage row 1 into rowbuf[1] ----
    {
        const float* r1 = lpn + rowstride;
        float4 a = *(const float4*)(r1);
        float4 b = *(const float4*)(r1 + 4);
        *(float4*)&rowbuf[1][8 * l]     = a;
        *(float4*)&rowbuf[1][8 * l + 4] = b;
    }
    // ---- prefetch rows 2..2+PF-1 into registers ----
    float4 ra[PF], rb[PF];
    const float* pf = lpn + 2 * rowstride;
    #pragma unroll
    for (int u = 0; u < PF; ++u) {
        if (2 + u < TT) { ra[u] = *(const float4*)(pf); rb[u] = *(const float4*)(pf + 4); }
        pf += rowstride;
    }
    __syncthreads();
    // ---- gather row 1 values (blank + 4 labels) ----
    float gb  = rowbuf[1][0];
    float gl0 = rowbuf[1][cls[0]];
    float gl1 = rowbuf[1][cls[1]];
    float gl2 = rowbuf[1][cls[2]];
    float gl3 = rowbuf[1][cls[3]];

    int t = 1;
    while (t < tEnd) {
        #pragma unroll
        for (int u = 0; u < PF; ++u) {
            if (t < tEnd) {
                // convert row-t log-probs to probs (5 transcendentals)
                float pb = __expf(gb);
                float p0 = __expf(gl0);
                float p1 = __expf(gl1);
                float p2 = __expf(gl2);
                float p3 = __expf(gl3);

                // stage row t+1 from prefetch regs; refill prefetch slot
                const int cb = (t + 1) & 1;
                *(float4*)&rowbuf[cb][8 * l]     = ra[u];
                *(float4*)&rowbuf[cb][8 * l + 4] = rb[u];
                if (t + 1 + PF < TT) {
                    ra[u] = *(const float4*)(pf);
                    rb[u] = *(const float4*)(pf + 4);
                }
                pf += rowstride;

                // issue gathers for row t+1 now; latency hides under the update.
                // DS ops from one wave execute in order -> reads see the writes.
                gb  = rowbuf[cb][0];
                gl0 = rowbuf[cb][cls[0]];
                gl1 = rowbuf[cb][cls[1]];
                gl2 = rowbuf[cb][cls[2]];
                gl3 = rowbuf[cb][cls[3]];

                // cross-lane transfer: prev lane's state 8l-1, frame-converted
                float p7 = __shfl_up(S7, 1);
                float pm = __shfl_up(logM, 1);
                if (l == 0) p7 = 0.0f;              // state -1 does not exist
                if (!active && p7 > 0.0f) {         // first mass: adopt sender frame
                    logM = pm; active = true;
                }
                float d  = fminf(fmaxf(pm - logM, -126.0f), 127.0f);
                p7 *= __uint_as_float((unsigned)((int)d + 127) << 23);  // *2^d

                // alpha update, descending j so in-place reads see old values
                S7 = (S7 + S6 + allowm[3] * S5) * p3 * m7;
                S6 = (S6 + S5) * pb * m6;
                S5 = (S5 + S4 + allowm[2] * S3) * p2 * m5;
                S4 = (S4 + S3) * pb * m4;
                S3 = (S3 + S2 + allowm[1] * S1) * p1 * m3;
                S2 = (S2 + S1) * pb * m2;
                S1 = (S1 + S0 + allowm[0] * p7) * p0 * m1;
                S0 = (S0 + p7) * pb * m0;
                ++t;
            }
        }
        // ---- per-lane renorm every PF steps: exact power-of-2 scale ----
        float mx = fmaxf(fmaxf(fmaxf(S0,S1),fmaxf(S2,S3)),
                         fmaxf(fmaxf(S4,S5),fmaxf(S6,S7)));
        int e = (mx > 0.0f) ? ((int)(__float_as_uint(mx) >> 23) - 127) : 0;
        float sc = __uint_as_float((unsigned)(127 - e) << 23);   // 2^-e exactly
        logM += (float)e;
        S0*=sc; S1*=sc; S2*=sc; S3*=sc; S4*=sc; S5*=sc; S6*=sc; S7*=sc;
    }

    // ---- epilogue: dump alpha + logM to LDS, lane 0 computes the loss ----
    __syncthreads();
    {
        float4 d0 = {S0, S1, S2, S3};
        float4 d1 = {S4, S5, S6, S7};
        *(float4*)&rowbuf[0][8 * l]     = d0;
        *(float4*)&rowbuf[0][8 * l + 4] = d1;
        lmArr[l] = logM;
    }
    __syncthreads();
    if (l == 0) {
        int sA = 2 * tl - 1, sB = 2 * tl;
        float a  = rowbuf[0][sA];
        float b  = rowbuf[0][sB];
        float la = __logf(a) + lmArr[sA >> 3] * LN2;   // true log alpha
        float lb = __logf(b) + lmArr[sB >> 3] * LN2;
        float m  = fmaxf(la, lb);
        float loss = -(m + __logf(__expf(la - m) + __expf(lb - m)));
        loss_ws[n] = loss / (float)tl;
    }
}

__global__ void ctc_reduce(const float* __restrict__ loss_ws, float* __restrict__ out)
{
    float v = loss_ws[threadIdx.x];   // 64 threads = 1 wave
    #pragma unroll
    for (int off = 32; off > 0; off >>= 1)
        v += __shfl_down(v, off);
    if (threadIdx.x == 0)
        out[0] = v / (float)NN;
}

extern "C" void kernel_launch(void* const* d_in, const int* in_sizes, int n_in,
                              void* d_out, int out_size, void* d_ws, size_t ws_size,
                              hipStream_t stream)
{
    const float* lp      = (const float*)d_in[0];
    const int*   targets = (const int*)d_in[1];
    const int*   in_len  = (const int*)d_in[2];
    const int*   tgt_len = (const int*)d_in[3];
    float*       out     = (float*)d_out;
    float*       ws      = (float*)d_ws;

    hipLaunchKernelGGL(ctc_alpha, dim3(NN), dim3(64), 0, stream,
                       lp, targets, in_len, tgt_len, ws);
    hipLaunchKernelGGL(ctc_reduce, dim3(1), dim3(64), 0, stream, ws, out);
}

// Round 5
// 477.490 us; speedup vs baseline: 2.3852x; 2.3852x over previous
//
#include <hip/hip_runtime.h>

// Problem constants
#define TT 2000
#define NN 64
#define CC 512
#define SS 200
#define PF 8            // gather-prefetch depth (rows in flight) == renorm cadence
#define NCr (NN*CC)     // row stride in floats (t -> t+1)
#define LN2 0.69314718055994530942f

// One wave (64 lanes) per batch element. Lane l owns states 8l..8l+7, alpha
// in registers (linear domain, per-lane power-of-2 block floating point).
// Round-5 changes vs round 4:
//  - NO LDS in the main loop: the 5 columns each lane needs (blank + 4 label
//    classes) are time-invariant -> gather directly from global into a
//    statically-indexed 8-deep register pipeline (40 outstanding loads).
//  - Compile-time trip count (249 x 8 + 7), unconditional clamped loads, so
//    the compiler keeps the pipeline in VGPRs (round 4's VGPR=28 proved the
//    guarded version collapsed to load->wait->use, ~1850 cy/iter).
__global__ __launch_bounds__(64, 1)
void ctc_alpha(const float* __restrict__ lp,        // (T,N,C)
               const int*  __restrict__ targets,    // (N,S)
               const int*  __restrict__ in_len,     // (N)
               const int*  __restrict__ tgt_len,    // (N)
               float*      __restrict__ loss_ws)    // (N)
{
    const int n = blockIdx.x;
    const int l = threadIdx.x;          // lane 0..63

    __shared__ float dumpS[512];        // final alpha dump (epilogue only)
    __shared__ float lmArr[64];         // per-lane logM (epilogue only)

    const int tl   = tgt_len[n];
    const int smax = 2 * tl;            // highest state ever read out

    // ---- static lattice info: odd states j=1,3,5,7 -> label classes ----
    int   cls[4];
    float allowm[4];
    #pragma unroll
    for (int q = 0; q < 4; ++q) {
        int s    = 8 * l + 2 * q + 1;
        int pos  = (s - 1) >> 1;
        int posc = pos < SS ? pos : SS - 1;           // clamp lanes past L=401
        int c    = targets[n * SS + posc];
        int pp   = pos - 1 < 0 ? 0 : (pos - 1 < SS ? pos - 1 : SS - 1);
        int cp   = targets[n * SS + pp];
        cls[q]    = c;
        allowm[q] = (pos >= 1 && c != cp) ? 1.0f : 0.0f;   // skip s-2 -> s
    }
    // validity masks: states > smax must stay exactly 0 (they'd otherwise
    // dominate the renorm max and flush the readout corridor - round-3 bug)
    float m0 = (8*l+0 <= smax) ? 1.f : 0.f;
    float m1 = (8*l+1 <= smax) ? 1.f : 0.f;
    float m2 = (8*l+2 <= smax) ? 1.f : 0.f;
    float m3 = (8*l+3 <= smax) ? 1.f : 0.f;
    float m4 = (8*l+4 <= smax) ? 1.f : 0.f;
    float m5 = (8*l+5 <= smax) ? 1.f : 0.f;
    float m6 = (8*l+6 <= smax) ? 1.f : 0.f;
    float m7 = (8*l+7 <= smax) ? 1.f : 0.f;

    const int inlen = in_len[n];
    const float* base = lp + (size_t)n * CC;   // (t=0, n, col 0)

    // ---- alpha_0 ----
    float S0=0.f,S1=0.f,S2=0.f,S3=0.f,S4=0.f,S5=0.f,S6=0.f,S7=0.f;
    bool active = (l == 0);
    if (l == 0) {
        S0 = __expf(base[0]);        // state 0: blank
        S1 = __expf(base[cls[0]]);   // state 1: first label
    }
    float logM = 0.0f;               // per-lane log2 scale (true = S * 2^logM)

    // ---- preload gather pipeline: rows 1..PF ----
    float Gb[PF], G0[PF], G1[PF], G2[PF], G3[PF];
    #pragma unroll
    for (int u = 0; u < PF; ++u) {
        const float* r = base + (size_t)(1 + u) * NCr;
        Gb[u]=r[0]; G0[u]=r[cls[0]]; G1[u]=r[cls[1]]; G2[u]=r[cls[2]]; G3[u]=r[cls[3]];
    }

    int t = 1;

#define STEP(u) do {                                                          \
    float pb=__expf(Gb[u]), q0=__expf(G0[u]), q1=__expf(G1[u]),               \
          q2=__expf(G2[u]), q3=__expf(G3[u]);                                 \
    int rowpf = (t + PF < TT) ? (t + PF) : (TT - 1);    /* clamp; dup unused */\
    const float* r_ = base + (size_t)rowpf * NCr;                             \
    Gb[u]=r_[0]; G0[u]=r_[cls[0]]; G1[u]=r_[cls[1]];                          \
    G2[u]=r_[cls[2]]; G3[u]=r_[cls[3]];                                       \
    float p7 = __shfl_up(S7, 1);          /* prev lane's state 8l-1 */        \
    float fm = __shfl_up(logM, 1);                                            \
    if (l == 0) p7 = 0.0f;                                                    \
    if (!active && p7 > 0.0f) { logM = fm; active = true; }                   \
    float dd = fminf(fmaxf(fm - logM, -126.0f), 127.0f);                      \
    p7 *= __uint_as_float((unsigned)((int)dd + 127) << 23);  /* * 2^dd */     \
    float n7=(S7+S6+allowm[3]*S5)*q3*m7;                                      \
    float n6=(S6+S5)*pb*m6;                                                   \
    float n5=(S5+S4+allowm[2]*S3)*q2*m5;                                      \
    float n4=(S4+S3)*pb*m4;                                                   \
    float n3=(S3+S2+allowm[1]*S1)*q1*m3;                                      \
    float n2=(S2+S1)*pb*m2;                                                   \
    float n1=(S1+S0+allowm[0]*p7)*q0*m1;                                      \
    float n0=(S0+p7)*pb*m0;                                                   \
    bool upd = t < inlen;                 /* freeze past input length */      \
    S7=upd?n7:S7; S6=upd?n6:S6; S5=upd?n5:S5; S4=upd?n4:S4;                   \
    S3=upd?n3:S3; S2=upd?n2:S2; S1=upd?n1:S1; S0=upd?n0:S0;                   \
    ++t;                                                                      \
} while (0)

#define RENORM do {                                                           \
    float mx = fmaxf(fmaxf(fmaxf(S0,S1),fmaxf(S2,S3)),                        \
                     fmaxf(fmaxf(S4,S5),fmaxf(S6,S7)));                       \
    int e = (mx > 0.0f) ? ((int)(__float_as_uint(mx) >> 23) - 127) : 0;       \
    float sc = __uint_as_float((unsigned)(127 - e) << 23);   /* 2^-e */       \
    logM += (float)e;                                                         \
    S0*=sc;S1*=sc;S2*=sc;S3*=sc;S4*=sc;S5*=sc;S6*=sc;S7*=sc;                  \
} while (0)

    // 1999 steps = 249 full blocks of 8 (+renorm) + 7-step tail
    for (int tb = 0; tb < 249; ++tb) {
        STEP(0); STEP(1); STEP(2); STEP(3);
        STEP(4); STEP(5); STEP(6); STEP(7);
        RENORM;
    }
    STEP(0); STEP(1); STEP(2); STEP(3); STEP(4); STEP(5); STEP(6);

#undef STEP
#undef RENORM

    // ---- epilogue ----
    __syncthreads();
    dumpS[8*l+0]=S0; dumpS[8*l+1]=S1; dumpS[8*l+2]=S2; dumpS[8*l+3]=S3;
    dumpS[8*l+4]=S4; dumpS[8*l+5]=S5; dumpS[8*l+6]=S6; dumpS[8*l+7]=S7;
    lmArr[l] = logM;
    __syncthreads();
    if (l == 0) {
        int sA = 2 * tl - 1, sB = 2 * tl;
        float a  = dumpS[sA];
        float b  = dumpS[sB];
        float la = __logf(a) + lmArr[sA >> 3] * LN2;   // true log alpha
        float lb = __logf(b) + lmArr[sB >> 3] * LN2;
        float m  = fmaxf(la, lb);
        float loss = -(m + __logf(__expf(la - m) + __expf(lb - m)));
        loss_ws[n] = loss / (float)tl;
    }
}

__global__ void ctc_reduce(const float* __restrict__ loss_ws, float* __restrict__ out)
{
    float v = loss_ws[threadIdx.x];   // 64 threads = 1 wave
    #pragma unroll
    for (int off = 32; off > 0; off >>= 1)
        v += __shfl_down(v, off);
    if (threadIdx.x == 0)
        out[0] = v / (float)NN;
}

extern "C" void kernel_launch(void* const* d_in, const int* in_sizes, int n_in,
                              void* d_out, int out_size, void* d_ws, size_t ws_size,
                              hipStream_t stream)
{
    const float* lp      = (const float*)d_in[0];
    const int*   targets = (const int*)d_in[1];
    const int*   in_len  = (const int*)d_in[2];
    const int*   tgt_len = (const int*)d_in[3];
    float*       out     = (float*)d_out;
    float*       ws      = (float*)d_ws;

    hipLaunchKernelGGL(ctc_alpha, dim3(NN), dim3(64), 0, stream,
                       lp, targets, in_len, tgt_len, ws);
    hipLaunchKernelGGL(ctc_reduce, dim3(1), dim3(64), 0, stream, ws, out);
}

// Round 6
// 361.345 us; speedup vs baseline: 3.1519x; 1.3214x over previous
//
#include <hip/hip_runtime.h>

// Problem constants
#define TT 2000
#define NN 64
#define CC 512
#define SS 200
#define PF 8            // scan prefetch depth == renorm cadence
#define LN2 0.69314718055994530942f

// ---------------- workspace layout (bytes) ----------------
// plabT : (N, T, 256) bf16  -> per-n contiguous stream for the scan
// pbT   : (N, T) float      -> blank probs
// tpad  : (N, 256) int      -> clamped gather columns
// loss  : (N) float
#define OFF_PLAB 0ull
#define SZ_PLAB  ((unsigned long long)NN * TT * 256 * 2)          // 65,536,000
#define OFF_PB   (OFF_PLAB + SZ_PLAB)
#define SZ_PB    ((unsigned long long)NN * TT * 4)                // 512,000
#define OFF_TPAD (OFF_PB + SZ_PB)
#define SZ_TPAD  ((unsigned long long)NN * 256 * 4)               // 65,536
#define OFF_LOSS (OFF_TPAD + SZ_TPAD)
#define SZ_LOSS  (NN * 4)
#define WS_NEED  (OFF_LOSS + SZ_LOSS)

__device__ __forceinline__ unsigned bf16rne(float x) {
    unsigned b = __float_as_uint(x);
    return (b + 0x7FFFu + ((b >> 16) & 1u)) >> 16;      // round-to-nearest-even
}

// ---- kernel 0: clamped column table tpad[n][j] = targets[n][min(j,199)] ----
__global__ void ctc_tpad(const int* __restrict__ targets, int* __restrict__ tpad)
{
    int n = blockIdx.x, j = threadIdx.x;
    tpad[n * 256 + j] = targets[n * SS + (j < SS ? j : SS - 1)];
}

// ---- kernel 1: compaction. grid=T blocks x 64 threads. For each (t,n):
// gather the 256 label log-probs (cols = tpad), exp, zero slots j>=tl (folds
// the odd-state validity mask into the data), pack bf16, write transposed.
__global__ __launch_bounds__(64, 1)
void ctc_compact(const float* __restrict__ lp,
                 const int*  __restrict__ tpad,
                 const int*  __restrict__ tgt_len,
                 unsigned*   __restrict__ plabT,   // (N,T,256) bf16 as uint pairs
                 float*      __restrict__ pbT)     // (N,T)
{
    const int t = blockIdx.x;
    const int l = threadIdx.x;
    const int j = 4 * l;

    #pragma unroll 4
    for (int n = 0; n < NN; ++n) {
        const float* row = lp + ((size_t)t * NN + n) * CC;
        int4 c = *(const int4*)(tpad + n * 256 + j);
        int  tl = tgt_len[n];
        float g0 = row[c.x], g1 = row[c.y], g2 = row[c.z], g3 = row[c.w];
        float q0 = (j + 0 < tl) ? __expf(g0) : 0.f;   // state 2j+1 valid iff j<tl
        float q1 = (j + 1 < tl) ? __expf(g1) : 0.f;
        float q2 = (j + 2 < tl) ? __expf(g2) : 0.f;
        float q3 = (j + 3 < tl) ? __expf(g3) : 0.f;
        unsigned wx = bf16rne(q0) | (bf16rne(q1) << 16);
        unsigned wy = bf16rne(q2) | (bf16rne(q3) << 16);
        unsigned* dst = plabT + ((size_t)n * TT + t) * 128;   // 256 bf16 = 128 uints
        dst[2 * l]     = wx;
        dst[2 * l + 1] = wy;
        if (l == 0) pbT[(size_t)n * TT + t] = __expf(row[0]);
    }
}

// ---- kernel 2: the serial scan. One wave per batch element; lane l owns
// states 8l..8l+7 in registers; per-lane power-of-2 block floating point.
// Consumes the compacted stream: 1 uint2 + 1 uniform float per step, no exp.
__global__ __launch_bounds__(64, 1)
void ctc_scan(const float*    __restrict__ pbT,
              const unsigned* __restrict__ plabT,
              const int*      __restrict__ targets,
              const int*      __restrict__ in_len,
              const int*      __restrict__ tgt_len,
              float*          __restrict__ loss_ws)
{
    const int n = blockIdx.x;
    const int l = threadIdx.x;

    __shared__ float dumpS[512];
    __shared__ float lmArr[64];

    const int tl = tgt_len[n];

    // skip-transition allow mask (odd states 8l+2q+1, label pos = 4l+q)
    float allowm[4];
    #pragma unroll
    for (int q = 0; q < 4; ++q) {
        int pos  = 4 * l + q;
        int posc = pos < SS ? pos : SS - 1;
        int pp   = pos - 1 < 0 ? 0 : (pos - 1 < SS ? pos - 1 : SS - 1);
        allowm[q] = (pos >= 1 && targets[n * SS + posc] != targets[n * SS + pp])
                    ? 1.0f : 0.0f;
    }
    // even-state validity: state 8l+2k alive iff 4l+k <= tl
    float me0 = (4*l+0 <= tl) ? 1.f : 0.f;
    float me1 = (4*l+1 <= tl) ? 1.f : 0.f;
    float me2 = (4*l+2 <= tl) ? 1.f : 0.f;
    float me3 = (4*l+3 <= tl) ? 1.f : 0.f;

    const int inlen = in_len[n];
    const float*    pbn = pbT   + (size_t)n * TT;
    const unsigned* pln = plabT + (size_t)n * TT * 128;   // row stride 128 uints

    // ---- alpha_0 from compacted row 0 ----
    uint2 w0 = *(const uint2*)(pln + 2 * l);
    float pb0 = pbn[0];
    float S0=0.f,S1=0.f,S2=0.f,S3=0.f,S4=0.f,S5=0.f,S6=0.f,S7=0.f;
    bool active = (l == 0);
    if (l == 0) {
        S0 = pb0;                                   // state 0: blank
        S1 = __uint_as_float(w0.x << 16);           // state 1: first label
    }
    float logM = 0.0f;

    // ---- preload pipeline: rows 1..PF ----
    float F[PF]; uint2 W[PF];
    #pragma unroll
    for (int u = 0; u < PF; ++u) {
        F[u] = pbn[1 + u];
        W[u] = *(const uint2*)(pln + (size_t)(1 + u) * 128 + 2 * l);
    }

    int t = 1;

#define STEP(u, FRZ) do {                                                     \
    float pb = F[u];                                                          \
    float q0 = __uint_as_float(W[u].x << 16);                                 \
    float q1 = __uint_as_float(W[u].x & 0xFFFF0000u);                         \
    float q2 = __uint_as_float(W[u].y << 16);                                 \
    float q3 = __uint_as_float(W[u].y & 0xFFFF0000u);                         \
    int rowpf = (t + PF < TT) ? (t + PF) : (TT - 1);                          \
    F[u] = pbn[rowpf];                                                        \
    W[u] = *(const uint2*)(pln + (size_t)rowpf * 128 + 2 * l);                \
    float p7 = __shfl_up(S7, 1);                                              \
    float fm = __shfl_up(logM, 1);                                            \
    if (l == 0) p7 = 0.0f;                                                    \
    if (!active && p7 > 0.0f) { logM = fm; active = true; }                   \
    float dd = fminf(fmaxf(fm - logM, -126.0f), 127.0f);                      \
    p7 *= __uint_as_float((unsigned)((int)dd + 127) << 23);                   \
    float n7=(S7+S6+allowm[3]*S5)*q3;                                         \
    float n6=(S6+S5)*pb*me3;                                                  \
    float n5=(S5+S4+allowm[2]*S3)*q2;                                         \
    float n4=(S4+S3)*pb*me2;                                                  \
    float n3=(S3+S2+allowm[1]*S1)*q1;                                         \
    float n2=(S2+S1)*pb*me1;                                                  \
    float n1=(S1+S0+allowm[0]*p7)*q0;                                         \
    float n0=(S0+p7)*pb*me0;                                                  \
    if (FRZ) {                                                                \
        bool upd = t < inlen;                                                 \
        S7=upd?n7:S7; S6=upd?n6:S6; S5=upd?n5:S5; S4=upd?n4:S4;               \
        S3=upd?n3:S3; S2=upd?n2:S2; S1=upd?n1:S1; S0=upd?n0:S0;               \
    } else {                                                                  \
        S7=n7; S6=n6; S5=n5; S4=n4; S3=n3; S2=n2; S1=n1; S0=n0;               \
    }                                                                         \
    ++t;                                                                      \
} while (0)

#define RENORM do {                                                           \
    float mx = fmaxf(fmaxf(fmaxf(S0,S1),fmaxf(S2,S3)),                        \
                     fmaxf(fmaxf(S4,S5),fmaxf(S6,S7)));                       \
    int e = (mx > 0.0f) ? ((int)(__float_as_uint(mx) >> 23) - 127) : 0;       \
    float sc = __uint_as_float((unsigned)(127 - e) << 23);                    \
    logM += (float)e;                                                         \
    S0*=sc;S1*=sc;S2*=sc;S3*=sc;S4*=sc;S5*=sc;S6*=sc;S7*=sc;                  \
} while (0)

    // 1999 steps = 249 x 8 (+renorm) + 7 tail
    if (inlen >= TT) {              // fast path: no freeze selects
        for (int tb = 0; tb < 249; ++tb) {
            STEP(0,0); STEP(1,0); STEP(2,0); STEP(3,0);
            STEP(4,0); STEP(5,0); STEP(6,0); STEP(7,0);
            RENORM;
        }
        STEP(0,0); STEP(1,0); STEP(2,0); STEP(3,0); STEP(4,0); STEP(5,0); STEP(6,0);
    } else {                        // general path (unused for this dataset)
        for (int tb = 0; tb < 249; ++tb) {
            STEP(0,1); STEP(1,1); STEP(2,1); STEP(3,1);
            STEP(4,1); STEP(5,1); STEP(6,1); STEP(7,1);
            RENORM;
        }
        STEP(0,1); STEP(1,1); STEP(2,1); STEP(3,1); STEP(4,1); STEP(5,1); STEP(6,1);
    }

#undef STEP
#undef RENORM

    // ---- epilogue ----
    __syncthreads();
    dumpS[8*l+0]=S0; dumpS[8*l+1]=S1; dumpS[8*l+2]=S2; dumpS[8*l+3]=S3;
    dumpS[8*l+4]=S4; dumpS[8*l+5]=S5; dumpS[8*l+6]=S6; dumpS[8*l+7]=S7;
    lmArr[l] = logM;
    __syncthreads();
    if (l == 0) {
        int sA = 2 * tl - 1, sB = 2 * tl;
        float a  = dumpS[sA];
        float b  = dumpS[sB];
        float la = __logf(a) + lmArr[sA >> 3] * LN2;
        float lb = __logf(b) + lmArr[sB >> 3] * LN2;
        float m  = fmaxf(la, lb);
        float loss = -(m + __logf(__expf(la - m) + __expf(lb - m)));
        loss_ws[n] = loss / (float)tl;
    }
}

// ---------------- fallback: round-5 single-kernel scan (proven, 477us) -----
#define NCr (NN*CC)
__global__ __launch_bounds__(64, 1)
void ctc_alpha_fb(const float* __restrict__ lp, const int* __restrict__ targets,
                  const int* __restrict__ in_len, const int* __restrict__ tgt_len,
                  float* __restrict__ loss_ws)
{
    const int n = blockIdx.x;
    const int l = threadIdx.x;
    __shared__ float dumpS[512];
    __shared__ float lmArr[64];
    const int tl   = tgt_len[n];
    const int smax = 2 * tl;
    int   cls[4];
    float allowm[4];
    #pragma unroll
    for (int q = 0; q < 4; ++q) {
        int s    = 8 * l + 2 * q + 1;
        int pos  = (s - 1) >> 1;
        int posc = pos < SS ? pos : SS - 1;
        int c    = targets[n * SS + posc];
        int pp   = pos - 1 < 0 ? 0 : (pos - 1 < SS ? pos - 1 : SS - 1);
        int cp   = targets[n * SS + pp];
        cls[q]    = c;
        allowm[q] = (pos >= 1 && c != cp) ? 1.0f : 0.0f;
    }
    float m0=(8*l+0<=smax)?1.f:0.f, m1=(8*l+1<=smax)?1.f:0.f;
    float m2=(8*l+2<=smax)?1.f:0.f, m3=(8*l+3<=smax)?1.f:0.f;
    float m4=(8*l+4<=smax)?1.f:0.f, m5=(8*l+5<=smax)?1.f:0.f;
    float m6=(8*l+6<=smax)?1.f:0.f, m7=(8*l+7<=smax)?1.f:0.f;
    const int inlen = in_len[n];
    const float* base = lp + (size_t)n * CC;
    float S0=0.f,S1=0.f,S2=0.f,S3=0.f,S4=0.f,S5=0.f,S6=0.f,S7=0.f;
    bool active = (l == 0);
    if (l == 0) { S0 = __expf(base[0]); S1 = __expf(base[cls[0]]); }
    float logM = 0.0f;
    float Gb[PF], G0[PF], G1[PF], G2[PF], G3[PF];
    #pragma unroll
    for (int u = 0; u < PF; ++u) {
        const float* r = base + (size_t)(1 + u) * NCr;
        Gb[u]=r[0]; G0[u]=r[cls[0]]; G1[u]=r[cls[1]]; G2[u]=r[cls[2]]; G3[u]=r[cls[3]];
    }
    int t = 1;
#define STEPF(u) do {                                                         \
    float pb=__expf(Gb[u]), q0=__expf(G0[u]), q1=__expf(G1[u]),               \
          q2=__expf(G2[u]), q3=__expf(G3[u]);                                 \
    int rowpf = (t + PF < TT) ? (t + PF) : (TT - 1);                          \
    const float* r_ = base + (size_t)rowpf * NCr;                             \
    Gb[u]=r_[0]; G0[u]=r_[cls[0]]; G1[u]=r_[cls[1]];                          \
    G2[u]=r_[cls[2]]; G3[u]=r_[cls[3]];                                       \
    float p7 = __shfl_up(S7, 1);                                              \
    float fm = __shfl_up(logM, 1);                                            \
    if (l == 0) p7 = 0.0f;                                                    \
    if (!active && p7 > 0.0f) { logM = fm; active = true; }                   \
    float dd = fminf(fmaxf(fm - logM, -126.0f), 127.0f);                      \
    p7 *= __uint_as_float((unsigned)((int)dd + 127) << 23);                   \
    float n7=(S7+S6+allowm[3]*S5)*q3*m7;                                      \
    float n6=(S6+S5)*pb*m6;                                                   \
    float n5=(S5+S4+allowm[2]*S3)*q2*m5;                                      \
    float n4=(S4+S3)*pb*m4;                                                   \
    float n3=(S3+S2+allowm[1]*S1)*q1*m3;                                      \
    float n2=(S2+S1)*pb*m2;                                                   \
    float n1=(S1+S0+allowm[0]*p7)*q0*m1;                                      \
    float n0=(S0+p7)*pb*m0;                                                   \
    bool upd = t < inlen;                                                     \
    S7=upd?n7:S7; S6=upd?n6:S6; S5=upd?n5:S5; S4=upd?n4:S4;                   \
    S3=upd?n3:S3; S2=upd?n2:S2; S1=upd?n1:S1; S0=upd?n0:S0;                   \
    ++t;                                                                      \
} while (0)
#define RENORMF do {                                                          \
    float mx = fmaxf(fmaxf(fmaxf(S0,S1),fmaxf(S2,S3)),                        \
                     fmaxf(fmaxf(S4,S5),fmaxf(S6,S7)));                       \
    int e = (mx > 0.0f) ? ((int)(__float_as_uint(mx) >> 23) - 127) : 0;       \
    float sc = __uint_as_float((unsigned)(127 - e) << 23);                    \
    logM += (float)e;                                                         \
    S0*=sc;S1*=sc;S2*=sc;S3*=sc;S4*=sc;S5*=sc;S6*=sc;S7*=sc;                  \
} while (0)
    for (int tb = 0; tb < 249; ++tb) {
        STEPF(0); STEPF(1); STEPF(2); STEPF(3);
        STEPF(4); STEPF(5); STEPF(6); STEPF(7);
        RENORMF;
    }
    STEPF(0); STEPF(1); STEPF(2); STEPF(3); STEPF(4); STEPF(5); STEPF(6);
#undef STEPF
#undef RENORMF
    __syncthreads();
    dumpS[8*l+0]=S0; dumpS[8*l+1]=S1; dumpS[8*l+2]=S2; dumpS[8*l+3]=S3;
    dumpS[8*l+4]=S4; dumpS[8*l+5]=S5; dumpS[8*l+6]=S6; dumpS[8*l+7]=S7;
    lmArr[l] = logM;
    __syncthreads();
    if (l == 0) {
        int sA = 2 * tl - 1, sB = 2 * tl;
        float a  = dumpS[sA];
        float b  = dumpS[sB];
        float la = __logf(a) + lmArr[sA >> 3] * LN2;
        float lb = __logf(b) + lmArr[sB >> 3] * LN2;
        float m  = fmaxf(la, lb);
        float loss = -(m + __logf(__expf(la - m) + __expf(lb - m)));
        loss_ws[n] = loss / (float)tl;
    }
}

__global__ void ctc_reduce(const float* __restrict__ loss_ws, float* __restrict__ out)
{
    float v = loss_ws[threadIdx.x];
    #pragma unroll
    for (int off = 32; off > 0; off >>= 1)
        v += __shfl_down(v, off);
    if (threadIdx.x == 0)
        out[0] = v / (float)NN;
}

extern "C" void kernel_launch(void* const* d_in, const int* in_sizes, int n_in,
                              void* d_out, int out_size, void* d_ws, size_t ws_size,
                              hipStream_t stream)
{
    const float* lp      = (const float*)d_in[0];
    const int*   targets = (const int*)d_in[1];
    const int*   in_len  = (const int*)d_in[2];
    const int*   tgt_len = (const int*)d_in[3];
    float*       out     = (float*)d_out;
    char*        ws      = (char*)d_ws;

    if (ws_size >= WS_NEED) {
        unsigned* plabT  = (unsigned*)(ws + OFF_PLAB);
        float*    pbT    = (float*)(ws + OFF_PB);
        int*      tpad   = (int*)(ws + OFF_TPAD);
        float*    lossws = (float*)(ws + OFF_LOSS);
        hipLaunchKernelGGL(ctc_tpad,    dim3(NN), dim3(256), 0, stream, targets, tpad);
        hipLaunchKernelGGL(ctc_compact, dim3(TT), dim3(64),  0, stream,
                           lp, tpad, tgt_len, plabT, pbT);
        hipLaunchKernelGGL(ctc_scan,    dim3(NN), dim3(64),  0, stream,
                           pbT, plabT, targets, in_len, tgt_len, lossws);
        hipLaunchKernelGGL(ctc_reduce,  dim3(1),  dim3(64),  0, stream, lossws, out);
    } else {
        float* lossws = (float*)ws;   // only 256 B needed
        hipLaunchKernelGGL(ctc_alpha_fb, dim3(NN), dim3(64), 0, stream,
                           lp, targets, in_len, tgt_len, lossws);
        hipLaunchKernelGGL(ctc_reduce,   dim3(1),  dim3(64), 0, stream, lossws, out);
    }
}

// Round 7
// 275.341 us; speedup vs baseline: 4.1364x; 1.3124x over previous
//
#include <hip/hip_runtime.h>

// Problem constants
#define TT 2000
#define NN 64
#define CC 512
#define SS 200
#define NP 1000          // timestep pairs in the compacted stream
#define PF 8             // fallback prefetch depth
#define LN2 0.69314718055994530942f

// ---------------- workspace layout (bytes) ----------------
// plab4 : (N, NP, 64) uint4  -> pair-interleaved bf16 label probs
//         lane l, pair p: {q(t=2p+1) lo,hi , q(t=2p+2) lo,hi} (4 bf16 each)
// pbP   : (N, NP) float2     -> blank probs for (2p+1, 2p+2)
// tpad  : (N, 256) int       -> clamped gather columns
// loss  : (N) float
#define OFF_PLAB 0ull
#define SZ_PLAB  ((unsigned long long)NN * NP * 64 * 16)          // 65,536,000
#define OFF_PB   (OFF_PLAB + SZ_PLAB)
#define SZ_PB    ((unsigned long long)NN * NP * 8)                // 512,000
#define OFF_TPAD (OFF_PB + SZ_PB)
#define SZ_TPAD  ((unsigned long long)NN * 256 * 4)               // 65,536
#define OFF_LOSS (OFF_TPAD + SZ_TPAD)
#define SZ_LOSS  (NN * 4)
#define WS_NEED  (OFF_LOSS + SZ_LOSS)

__device__ __forceinline__ unsigned bf16rne(float x) {
    unsigned b = __float_as_uint(x);
    return (b + 0x7FFFu + ((b >> 16) & 1u)) >> 16;      // round-to-nearest-even
}

// ---- kernel 0: clamped column table tpad[n][j] = targets[n][min(j,199)] ----
__global__ void ctc_tpad(const int* __restrict__ targets, int* __restrict__ tpad)
{
    int n = blockIdx.x, j = threadIdx.x;
    tpad[n * 256 + j] = targets[n * SS + (j < SS ? j : SS - 1)];
}

// ---- kernel 1: compaction, pair-interleaved. grid=(NP,16) x 64 threads.
// Pair p covers t=2p+1 and t=2p+2 (clamped). Each block handles 4 n.
__global__ __launch_bounds__(64, 1)
void ctc_compact(const float* __restrict__ lp,
                 const int*  __restrict__ tpad,
                 const int*  __restrict__ tgt_len,
                 uint4*      __restrict__ plab4,
                 float2*     __restrict__ pbP)
{
    const int p  = blockIdx.x;
    const int l  = threadIdx.x;
    const int j  = 4 * l;
    const int ta = 2 * p + 1;
    const int tb = (2 * p + 2 < TT) ? (2 * p + 2) : (TT - 1);

    #pragma unroll
    for (int k = 0; k < 4; ++k) {
        const int n = blockIdx.y * 4 + k;
        const float* rowa = lp + ((size_t)ta * NN + n) * CC;
        const float* rowb = lp + ((size_t)tb * NN + n) * CC;
        const int4 c  = *(const int4*)(tpad + n * 256 + j);
        const int  tl = tgt_len[n];
        // odd-state validity (state 2j+1 <= 2tl  <=>  j < tl) folded into data
        float a0 = (j + 0 < tl) ? __expf(rowa[c.x]) : 0.f;
        float a1 = (j + 1 < tl) ? __expf(rowa[c.y]) : 0.f;
        float a2 = (j + 2 < tl) ? __expf(rowa[c.z]) : 0.f;
        float a3 = (j + 3 < tl) ? __expf(rowa[c.w]) : 0.f;
        float b0 = (j + 0 < tl) ? __expf(rowb[c.x]) : 0.f;
        float b1 = (j + 1 < tl) ? __expf(rowb[c.y]) : 0.f;
        float b2 = (j + 2 < tl) ? __expf(rowb[c.z]) : 0.f;
        float b3 = (j + 3 < tl) ? __expf(rowb[c.w]) : 0.f;
        uint4 w;
        w.x = bf16rne(a0) | (bf16rne(a1) << 16);
        w.y = bf16rne(a2) | (bf16rne(a3) << 16);
        w.z = bf16rne(b0) | (bf16rne(b1) << 16);
        w.w = bf16rne(b2) | (bf16rne(b3) << 16);
        plab4[((size_t)n * NP + p) * 64 + l] = w;
        if (l == 0)
            pbP[(size_t)n * NP + p] = make_float2(__expf(rowa[0]), __expf(rowb[0]));
    }
}

// ---- kernel 2: serial scan. One wave per n; lane l owns states 8l..8l+7.
// Linear domain, per-lane power-of-2 block floating point. Frame conversion
// for the cross-lane transfer is hoisted to block (8-step) boundaries: logM
// only changes at RENORM, so 2^(logM_{l-1}-logM_l) is a per-block constant.
// Per step: 1 shfl + 1 mul + the 8-state update. No per-step logM shfl.
__global__ __launch_bounds__(64, 1)
void ctc_scan(const float*  __restrict__ lp,
              const uint4*  __restrict__ plab4,
              const float2* __restrict__ pbP,
              const int*    __restrict__ targets,
              const int*    __restrict__ in_len,
              const int*    __restrict__ tgt_len,
              float*        __restrict__ loss_ws)
{
    const int n = blockIdx.x;
    const int l = threadIdx.x;

    __shared__ float dumpS[512];
    __shared__ float lmArr[64];

    const int tl = tgt_len[n];

    // skip-transition allow mask (odd state 8l+2q+1 <-> label pos 4l+q)
    float allowm[4];
    #pragma unroll
    for (int q = 0; q < 4; ++q) {
        int pos  = 4 * l + q;
        int posc = pos < SS ? pos : SS - 1;
        int pp   = pos - 1 < 0 ? 0 : (pos - 1 < SS ? pos - 1 : SS - 1);
        allowm[q] = (pos >= 1 && targets[n * SS + posc] != targets[n * SS + pp])
                    ? 1.0f : 0.0f;
    }
    // even-state validity: state 8l+2k alive iff 4l+k <= tl
    const float me0 = (4*l+0 <= tl) ? 1.f : 0.f;
    const float me1 = (4*l+1 <= tl) ? 1.f : 0.f;
    const float me2 = (4*l+2 <= tl) ? 1.f : 0.f;
    const float me3 = (4*l+3 <= tl) ? 1.f : 0.f;

    const int inlen = in_len[n];
    const uint4*  pw  = plab4 + (size_t)n * NP * 64 + l;
    const float2* pfn = pbP   + (size_t)n * NP;

    // ---- alpha_0 straight from lp row 0 ----
    float S0=0.f,S1=0.f,S2=0.f,S3=0.f,S4=0.f,S5=0.f,S6=0.f,S7=0.f;
    if (l == 0) {
        const float* row0 = lp + (size_t)n * CC;
        S0 = __expf(row0[0]);                    // state 0: blank
        S1 = __expf(row0[targets[n * SS]]);      // state 1: first label
    }
    float logM   = 0.0f;
    bool  activeB = (l == 0);
    float sc7e;

    // preload pairs 0..3
    uint4  WA = pw[0*64], WB = pw[1*64], WC = pw[2*64], WD = pw[3*64];
    float2 FA = pfn[0],   FB = pfn[1],   FC = pfn[2],   FD = pfn[3];

    int p = 0, t = 1;

#define BOUNDARY do {                                                         \
    float pm_ = __shfl_up(logM, 1);                                           \
    if (!activeB) logM = pm_;          /* adopt sender frame while empty */   \
    float dd_ = fminf(fmaxf(pm_ - logM, -126.0f), 127.0f);                    \
    sc7e = (l == 0) ? 0.0f                                                    \
         : __uint_as_float((unsigned)((int)dd_ + 127) << 23);  /* 2^dd */     \
} while (0)

#define ONESTEP(wlo, whi, pbv, FRZ) do {                                      \
    float q0 = __uint_as_float((wlo) << 16);                                  \
    float q1 = __uint_as_float((wlo) & 0xFFFF0000u);                          \
    float q2 = __uint_as_float((whi) << 16);                                  \
    float q3 = __uint_as_float((whi) & 0xFFFF0000u);                          \
    float pb = (pbv);                                                         \
    float p7 = __shfl_up(S7, 1) * sc7e;   /* frame-converted, 0 for lane0 */  \
    float n7=(S7+S6+allowm[3]*S5)*q3;                                         \
    float n6=(S6+S5)*pb*me3;                                                  \
    float n5=(S5+S4+allowm[2]*S3)*q2;                                         \
    float n4=(S4+S3)*pb*me2;                                                  \
    float n3=(S3+S2+allowm[1]*S1)*q1;                                         \
    float n2=(S2+S1)*pb*me1;                                                  \
    float n1=(S1+S0+allowm[0]*p7)*q0;                                         \
    float n0=(S0+p7)*pb*me0;                                                  \
    if (FRZ) {                                                                \
        bool upd = t < inlen;                                                 \
        S7=upd?n7:S7; S6=upd?n6:S6; S5=upd?n5:S5; S4=upd?n4:S4;               \
        S3=upd?n3:S3; S2=upd?n2:S2; S1=upd?n1:S1; S0=upd?n0:S0;               \
    } else {                                                                  \
        S7=n7; S6=n6; S5=n5; S4=n4; S3=n3; S2=n2; S1=n1; S0=n0;               \
    }                                                                         \
    ++t;                                                                      \
} while (0)

#define PAIRF(Wv, Fv, FRZ, REFILL) do {                                       \
    ONESTEP(Wv.x, Wv.y, Fv.x, FRZ);                                           \
    ONESTEP(Wv.z, Wv.w, Fv.y, FRZ);                                           \
    if (REFILL) {                                                             \
        int pr_ = p + 4; pr_ = pr_ < NP ? pr_ : NP - 1;                       \
        Wv = pw[(size_t)pr_ * 64];                                            \
        Fv = pfn[pr_];                                                        \
    }                                                                         \
    ++p;                                                                      \
} while (0)

#define RENORM do {                                                           \
    float mx = fmaxf(fmaxf(fmaxf(S0,S1),fmaxf(S2,S3)),                        \
                     fmaxf(fmaxf(S4,S5),fmaxf(S6,S7)));                       \
    int e = (mx > 0.0f) ? ((int)(__float_as_uint(mx) >> 23) - 127) : 0;       \
    float sc = __uint_as_float((unsigned)(127 - e) << 23);   /* 2^-e */       \
    logM += (float)e;                                                         \
    S0*=sc;S1*=sc;S2*=sc;S3*=sc;S4*=sc;S5*=sc;S6*=sc;S7*=sc;                  \
    activeB = mx > 0.0f;                                                      \
} while (0)

    BOUNDARY;   // initial frame constants (all logM==0 -> sc7e = 1 or 0)

    if (inlen >= TT) {          // fast path (this dataset: input_lengths == T)
        for (int b = 0; b < 249; ++b) {
            PAIRF(WA,FA,0,1); PAIRF(WB,FB,0,1);
            PAIRF(WC,FC,0,1); PAIRF(WD,FD,0,1);
            RENORM; BOUNDARY;
        }
        // tail: slots hold pairs 996..999 -> 3 full pairs + 1 single step
        PAIRF(WA,FA,0,0); PAIRF(WB,FB,0,0); PAIRF(WC,FC,0,0);
        ONESTEP(WD.x, WD.y, FD.x, 0);          // t = 1999
    } else {                    // general path with per-step freeze
        for (int b = 0; b < 249; ++b) {
            PAIRF(WA,FA,1,1); PAIRF(WB,FB,1,1);
            PAIRF(WC,FC,1,1); PAIRF(WD,FD,1,1);
            RENORM; BOUNDARY;
        }
        PAIRF(WA,FA,1,0); PAIRF(WB,FB,1,0); PAIRF(WC,FC,1,0);
        ONESTEP(WD.x, WD.y, FD.x, 1);
    }

#undef BOUNDARY
#undef ONESTEP
#undef PAIRF
#undef RENORM

    // ---- epilogue ----
    __syncthreads();
    dumpS[8*l+0]=S0; dumpS[8*l+1]=S1; dumpS[8*l+2]=S2; dumpS[8*l+3]=S3;
    dumpS[8*l+4]=S4; dumpS[8*l+5]=S5; dumpS[8*l+6]=S6; dumpS[8*l+7]=S7;
    lmArr[l] = logM;
    __syncthreads();
    if (l == 0) {
        int sA = 2 * tl - 1, sB = 2 * tl;
        float a  = dumpS[sA];
        float b  = dumpS[sB];
        float la = __logf(a) + lmArr[sA >> 3] * LN2;
        float lb = __logf(b) + lmArr[sB >> 3] * LN2;
        float m  = fmaxf(la, lb);
        float loss = -(m + __logf(__expf(la - m) + __expf(lb - m)));
        loss_ws[n] = loss / (float)tl;
    }
}

// ---------------- fallback: round-5 single-kernel scan (proven) ------------
#define NCr (NN*CC)
__global__ __launch_bounds__(64, 1)
void ctc_alpha_fb(const float* __restrict__ lp, const int* __restrict__ targets,
                  const int* __restrict__ in_len, const int* __restrict__ tgt_len,
                  float* __restrict__ loss_ws)
{
    const int n = blockIdx.x;
    const int l = threadIdx.x;
    __shared__ float dumpS[512];
    __shared__ float lmArr[64];
    const int tl   = tgt_len[n];
    const int smax = 2 * tl;
    int   cls[4];
    float allowm[4];
    #pragma unroll
    for (int q = 0; q < 4; ++q) {
        int s    = 8 * l + 2 * q + 1;
        int pos  = (s - 1) >> 1;
        int posc = pos < SS ? pos : SS - 1;
        int c    = targets[n * SS + posc];
        int pp   = pos - 1 < 0 ? 0 : (pos - 1 < SS ? pos - 1 : SS - 1);
        int cp   = targets[n * SS + pp];
        cls[q]    = c;
        allowm[q] = (pos >= 1 && c != cp) ? 1.0f : 0.0f;
    }
    float m0=(8*l+0<=smax)?1.f:0.f, m1=(8*l+1<=smax)?1.f:0.f;
    float m2=(8*l+2<=smax)?1.f:0.f, m3=(8*l+3<=smax)?1.f:0.f;
    float m4=(8*l+4<=smax)?1.f:0.f, m5=(8*l+5<=smax)?1.f:0.f;
    float m6=(8*l+6<=smax)?1.f:0.f, m7=(8*l+7<=smax)?1.f:0.f;
    const int inlen = in_len[n];
    const float* base = lp + (size_t)n * CC;
    float S0=0.f,S1=0.f,S2=0.f,S3=0.f,S4=0.f,S5=0.f,S6=0.f,S7=0.f;
    bool active = (l == 0);
    if (l == 0) { S0 = __expf(base[0]); S1 = __expf(base[cls[0]]); }
    float logM = 0.0f;
    float Gb[PF], G0[PF], G1[PF], G2[PF], G3[PF];
    #pragma unroll
    for (int u = 0; u < PF; ++u) {
        const float* r = base + (size_t)(1 + u) * NCr;
        Gb[u]=r[0]; G0[u]=r[cls[0]]; G1[u]=r[cls[1]]; G2[u]=r[cls[2]]; G3[u]=r[cls[3]];
    }
    int t = 1;
#define STEPF(u) do {                                                         \
    float pb=__expf(Gb[u]), q0=__expf(G0[u]), q1=__expf(G1[u]),               \
          q2=__expf(G2[u]), q3=__expf(G3[u]);                                 \
    int rowpf = (t + PF < TT) ? (t + PF) : (TT - 1);                          \
    const float* r_ = base + (size_t)rowpf * NCr;                             \
    Gb[u]=r_[0]; G0[u]=r_[cls[0]]; G1[u]=r_[cls[1]];                          \
    G2[u]=r_[cls[2]]; G3[u]=r_[cls[3]];                                       \
    float p7 = __shfl_up(S7, 1);                                              \
    float fm = __shfl_up(logM, 1);                                            \
    if (l == 0) p7 = 0.0f;                                                    \
    if (!active && p7 > 0.0f) { logM = fm; active = true; }                   \
    float dd = fminf(fmaxf(fm - logM, -126.0f), 127.0f);                      \
    p7 *= __uint_as_float((unsigned)((int)dd + 127) << 23);                   \
    float n7=(S7+S6+allowm[3]*S5)*q3*m7;                                      \
    float n6=(S6+S5)*pb*m6;                                                   \
    float n5=(S5+S4+allowm[2]*S3)*q2*m5;                                      \
    float n4=(S4+S3)*pb*m4;                                                   \
    float n3=(S3+S2+allowm[1]*S1)*q1*m3;                                      \
    float n2=(S2+S1)*pb*m2;                                                   \
    float n1=(S1+S0+allowm[0]*p7)*q0*m1;                                      \
    float n0=(S0+p7)*pb*m0;                                                   \
    bool upd = t < inlen;                                                     \
    S7=upd?n7:S7; S6=upd?n6:S6; S5=upd?n5:S5; S4=upd?n4:S4;                   \
    S3=upd?n3:S3; S2=upd?n2:S2; S1=upd?n1:S1; S0=upd?n0:S0;                   \
    ++t;                                                                      \
} while (0)
#define RENORMF do {                                                          \
    float mx = fmaxf(fmaxf(fmaxf(S0,S1),fmaxf(S2,S3)),                        \
                     fmaxf(fmaxf(S4,S5),fmaxf(S6,S7)));                       \
    int e = (mx > 0.0f) ? ((int)(__float_as_uint(mx) >> 23) - 127) : 0;       \
    float sc = __uint_as_float((unsigned)(127 - e) << 23);                    \
    logM += (float)e;                                                         \
    S0*=sc;S1*=sc;S2*=sc;S3*=sc;S4*=sc;S5*=sc;S6*=sc;S7*=sc;                  \
} while (0)
    for (int tb = 0; tb < 249; ++tb) {
        STEPF(0); STEPF(1); STEPF(2); STEPF(3);
        STEPF(4); STEPF(5); STEPF(6); STEPF(7);
        RENORMF;
    }
    STEPF(0); STEPF(1); STEPF(2); STEPF(3); STEPF(4); STEPF(5); STEPF(6);
#undef STEPF
#undef RENORMF
    __syncthreads();
    dumpS[8*l+0]=S0; dumpS[8*l+1]=S1; dumpS[8*l+2]=S2; dumpS[8*l+3]=S3;
    dumpS[8*l+4]=S4; dumpS[8*l+5]=S5; dumpS[8*l+6]=S6; dumpS[8*l+7]=S7;
    lmArr[l] = logM;
    __syncthreads();
    if (l == 0) {
        int sA = 2 * tl - 1, sB = 2 * tl;
        float a  = dumpS[sA];
        float b  = dumpS[sB];
        float la = __logf(a) + lmArr[sA >> 3] * LN2;
        float lb = __logf(b) + lmArr[sB >> 3] * LN2;
        float m  = fmaxf(la, lb);
        float loss = -(m + __logf(__expf(la - m) + __expf(lb - m)));
        loss_ws[n] = loss / (float)tl;
    }
}

__global__ void ctc_reduce(const float* __restrict__ loss_ws, float* __restrict__ out)
{
    float v = loss_ws[threadIdx.x];
    #pragma unroll
    for (int off = 32; off > 0; off >>= 1)
        v += __shfl_down(v, off);
    if (threadIdx.x == 0)
        out[0] = v / (float)NN;
}

extern "C" void kernel_launch(void* const* d_in, const int* in_sizes, int n_in,
                              void* d_out, int out_size, void* d_ws, size_t ws_size,
                              hipStream_t stream)
{
    const float* lp      = (const float*)d_in[0];
    const int*   targets = (const int*)d_in[1];
    const int*   in_len  = (const int*)d_in[2];
    const int*   tgt_len = (const int*)d_in[3];
    float*       out     = (float*)d_out;
    char*        ws      = (char*)d_ws;

    if (ws_size >= WS_NEED) {
        uint4*  plab4  = (uint4*)(ws + OFF_PLAB);
        float2* pbP    = (float2*)(ws + OFF_PB);
        int*    tpad   = (int*)(ws + OFF_TPAD);
        float*  lossws = (float*)(ws + OFF_LOSS);
        hipLaunchKernelGGL(ctc_tpad,    dim3(NN), dim3(256), 0, stream, targets, tpad);
        hipLaunchKernelGGL(ctc_compact, dim3(NP, 16), dim3(64), 0, stream,
                           lp, tpad, tgt_len, plab4, pbP);
        hipLaunchKernelGGL(ctc_scan,    dim3(NN), dim3(64),  0, stream,
                           lp, plab4, pbP, targets, in_len, tgt_len, lossws);
        hipLaunchKernelGGL(ctc_reduce,  dim3(1),  dim3(64),  0, stream, lossws, out);
    } else {
        float* lossws = (float*)ws;   // only 256 B needed
        hipLaunchKernelGGL(ctc_alpha_fb, dim3(NN), dim3(64), 0, stream,
                           lp, targets, in_len, tgt_len, lossws);
        hipLaunchKernelGGL(ctc_reduce,   dim3(1),  dim3(64), 0, stream, lossws, out);
    }
}